// Round 3
// baseline (14669.077 us; speedup 1.0000x reference)
//
#include <hip/hip_runtime.h>
#include <hip/hip_bf16.h>
#include <math.h>

// Problem constants (N_WAY=64, K_SHOT=5, Q_QUERY=128, D_FEAT=128)
#define M     8192      // n*q query rows
#define D     128       // feature dim
#define NCLS  64        // n classes
#define KSHOT 5
#define XROW  133       // (k+q) rows per class in x
#define KTOP  9
#define EPSV  1e-8f

// k2 config: 64 i-rows/block (one per LANE, shared by all 8 waves),
// 2 j-splits, j-tiles of 64 rows double-buffered in LDS.
#define IB    64
#define W2    8
#define TPB2  (W2 * 64)     // 512
#define SJ2   2
#define TJ    64            // j rows per LDS tile
#define JPB   (M / SJ2)     // 4096 j per block
#define NTILE (JPB / TJ)    // 64 tiles
#define JW    8             // j rows per wave per tile
#define NPART (SJ2 * W2)    // 16 partial top-9 lists per i-row

// ---------------------------------------------------------------------------
// register-resident top-9 with (value desc, index asc) tie-break, matching
// jax.lax.top_k set semantics. Fully unrolled -> static indexing -> VGPRs.
__device__ __forceinline__ void top9_insert(float (&kv)[KTOP], int (&ki)[KTOP],
                                            float v, int j) {
  if (v > kv[KTOP - 1] || (v == kv[KTOP - 1] && j < ki[KTOP - 1])) {
    float cv = v; int cj = j;
#pragma unroll
    for (int t = 0; t < KTOP; ++t) {
      bool b = (cv > kv[t]) || (cv == kv[t] && cj < ki[t]);
      float tv = kv[t]; int ti = ki[t];
      kv[t] = b ? cv : tv;  ki[t] = b ? cj : ti;
      cv   = b ? tv : cv;   cj   = b ? ti : cj;
    }
  }
}

// ---------------------------------------------------------------------------
// k0: class prototypes = mean of 5 support rows, L2-normalized, stored
// TRANSPOSED protnT[d][c] so k3's per-lane-class reads are coalesced.
__global__ void k0_proto(const float* __restrict__ x, float* __restrict__ protnT) {
  int c = blockIdx.x;
  int lane = threadIdx.x;
  const float* base = x + (size_t)(c * XROW) * D;
  float a0 = 0.f, a1 = 0.f;
#pragma unroll
  for (int s = 0; s < KSHOT; ++s) {
    a0 += base[s * D + lane];
    a1 += base[s * D + 64 + lane];
  }
  a0 *= 0.2f; a1 *= 0.2f;
  float ss = a0 * a0 + a1 * a1;
#pragma unroll
  for (int off = 1; off < 64; off <<= 1) ss += __shfl_xor(ss, off);
  float rn = 1.0f / fmaxf(sqrtf(ss), EPSV);
  protnT[lane * NCLS + c]        = a0 * rn;
  protnT[(lane + 64) * NCLS + c] = a1 * rn;
}

// ---------------------------------------------------------------------------
// k1: L2-normalize the 8192 query rows into qn (row-major, 4 MB).
__global__ void k1_qnorm(const float* __restrict__ x, float* __restrict__ qn) {
  int lane = threadIdx.x & 63;
  int wv = threadIdx.x >> 6;
  int r = blockIdx.x * 4 + wv;
  int xr = (r >> 7) * XROW + KSHOT + (r & 127);
  const float* src = x + (size_t)xr * D;
  float v0 = src[lane], v1 = src[64 + lane];
  float ss = v0 * v0 + v1 * v1;
#pragma unroll
  for (int off = 1; off < 64; off <<= 1) ss += __shfl_xor(ss, off);
  float rn = 1.0f / fmaxf(sqrtf(ss), EPSV);
  qn[(size_t)r * D + lane]      = v0 * rn;
  qn[(size_t)r * D + 64 + lane] = v1 * rn;
}

// ---------------------------------------------------------------------------
// async 16B global -> LDS (contiguous slab copy, coalesced, no VGPR roundtrip)
__device__ __forceinline__ void stage_tile(const float* __restrict__ src,
                                           float* dst, int tid) {
#pragma unroll
  for (int k = 0; k < 4; ++k) {
    int flat = k * TPB2 + tid;          // float4 index; lds = uniform + lane*16
    __builtin_amdgcn_global_load_lds(
        (const __attribute__((address_space(1))) void*)(src + (size_t)flat * 4),
        (__attribute__((address_space(3))) void*)(dst + (size_t)flat * 4),
        16, 0, 0);
  }
}

// ---------------------------------------------------------------------------
// k2: heavy pass. Lane's own qn row lives in 32 float4 REGISTERS (no a-loads).
// j-tile (64 rows, 32 KB, contiguous in qn) double-buffered in LDS via
// global_load_lds; in-loop B reads are wave-uniform ds_read_b128 (broadcast,
// conflict-free). Per chunk: 8 ds_read + 32 v_fma -> VALU-bound.
__global__ __launch_bounds__(TPB2, 2) void
k2_topk(const float* __restrict__ qn, float* __restrict__ pkv, int* __restrict__ pki) {
  __shared__ float Bs[2][TJ * D];       // 2 x 32 KB

  const int tid  = threadIdx.x;
  const int lane = tid & 63;
  const int wv   = tid >> 6;
  const int ib   = blockIdx.x >> 1;     // 128 i-blocks
  const int js   = blockIdx.x & 1;      // 2 j-splits
  const int i    = ib * IB + lane;
  const int jbase0 = js * JPB;

  // own (normalized) query row -> registers, statically indexed
  float4 areg[32];
  {
    const float4* arow = (const float4*)(qn + (size_t)i * D);
#pragma unroll
    for (int c = 0; c < 32; ++c) areg[c] = arow[c];
  }

  float kv[KTOP]; int ki[KTOP];
#pragma unroll
  for (int t = 0; t < KTOP; ++t) { kv[t] = -INFINITY; ki[t] = 0x7fffffff; }

  // prologue: stage tile 0
  stage_tile(qn + (size_t)jbase0 * D, Bs[0], tid);
  asm volatile("s_waitcnt vmcnt(0)" ::: "memory");
  __syncthreads();

  for (int t = 0; t < NTILE; ++t) {
    const int cur = t & 1;
    if (t + 1 < NTILE)
      stage_tile(qn + (size_t)(jbase0 + (t + 1) * TJ) * D, Bs[cur ^ 1], tid);

    const float4* bb = (const float4*)(Bs[cur] + (size_t)(wv * JW) * D);
    float acc[JW];
#pragma unroll
    for (int u = 0; u < JW; ++u) acc[u] = 0.f;

#pragma unroll
    for (int c = 0; c < 32; ++c) {
      float4 a = areg[c];
#pragma unroll
      for (int u = 0; u < JW; ++u) {
        float4 b = bb[u * 32 + c];      // wave-uniform broadcast ds_read_b128
        acc[u] += a.x * b.x + a.y * b.y + a.z * b.z + a.w * b.w;
      }
    }

    const int j0 = jbase0 + t * TJ + wv * JW;
#pragma unroll
    for (int u = 0; u < JW; ++u) top9_insert(kv, ki, acc[u], j0 + u);

    asm volatile("s_waitcnt vmcnt(0)" ::: "memory");   // staging loads landed
    __syncthreads();                                   // all waves done reading
  }

  const int p = js * W2 + wv;
  size_t base = ((size_t)i * NPART + p) * KTOP;
#pragma unroll
  for (int t = 0; t < KTOP; ++t) { pkv[base + t] = kv[t]; pki[base + t] = ki[t]; }
}

// ---------------------------------------------------------------------------
// k_merge: per row, merge the 16 partial top-9 lists (disjoint j-ranges).
__global__ void k_merge(const float* __restrict__ pkv, const int* __restrict__ pki,
                        float* __restrict__ kval, int* __restrict__ kidx) {
  int i = blockIdx.x * blockDim.x + threadIdx.x;
  float kv[KTOP]; int ki[KTOP];
#pragma unroll
  for (int t = 0; t < KTOP; ++t) { kv[t] = -INFINITY; ki[t] = 0x7fffffff; }
  const float* pv = pkv + (size_t)i * NPART * KTOP;
  const int*   pi = pki + (size_t)i * NPART * KTOP;
  for (int t = 0; t < NPART * KTOP; ++t) top9_insert(kv, ki, pv[t], pi[t]);
#pragma unroll
  for (int t = 0; t < KTOP; ++t) {
    kval[(size_t)i * KTOP + t] = kv[t];
    kidx[(size_t)i * KTOP + t] = ki[t];
  }
}

// ---------------------------------------------------------------------------
// k3: mutual mask + softmax over <=9 entries + adapted query + normalize +
// project on normalized prototypes, scale by tao. One wave per query row.
__global__ void k3_out(const float* __restrict__ x, const float* __restrict__ kval,
                       const int* __restrict__ kidx, const float* __restrict__ protnT,
                       const float* __restrict__ taop, float* __restrict__ out) {
  __shared__ float sw[4][KTOP];
  __shared__ int   sj[4][KTOP];
  __shared__ float an[4][D];
  int lane = threadIdx.x & 63;
  int wv   = threadIdx.x >> 6;
  int i = blockIdx.x * 4 + wv;

  float v = -INFINITY; int jt = 0; bool mut = false;
  if (lane < KTOP) {
    v  = kval[(size_t)i * KTOP + lane];
    jt = kidx[(size_t)i * KTOP + lane];
    const int* oj = kidx + (size_t)jt * KTOP;
#pragma unroll
    for (int t = 0; t < KTOP; ++t) mut = mut || (oj[t] == i);
  }
  float lv = mut ? v : -INFINITY;
#pragma unroll
  for (int off = 1; off < 16; off <<= 1) lv = fmaxf(lv, __shfl_xor(lv, off));
  float wexp = mut ? expf(v - lv) : 0.f;    // self is always mutual -> z >= 1
  float z = wexp;
#pragma unroll
  for (int off = 1; off < 16; off <<= 1) z += __shfl_xor(z, off);
  if (lane < KTOP) { sw[wv][lane] = wexp / z; sj[wv][lane] = jt; }
  __syncthreads();

  float a0 = 0.f, a1 = 0.f;
#pragma unroll
  for (int t = 0; t < KTOP; ++t) {
    float wt = sw[wv][t];
    if (wt != 0.f) {
      int j = sj[wv][t];
      int xr = (j >> 7) * XROW + KSHOT + (j & 127);
      const float* qr = x + (size_t)xr * D;
      a0 += wt * qr[lane];
      a1 += wt * qr[64 + lane];
    }
  }
  float ss = a0 * a0 + a1 * a1;
#pragma unroll
  for (int off = 1; off < 64; off <<= 1) ss += __shfl_xor(ss, off);
  float rn = 1.0f / fmaxf(sqrtf(ss), EPSV);
  an[wv][lane]      = a0 * rn;
  an[wv][64 + lane] = a1 * rn;
  __syncthreads();

  float acc = 0.f;
#pragma unroll 8
  for (int d = 0; d < D; ++d) acc += an[wv][d] * protnT[d * NCLS + lane];
  out[(size_t)i * NCLS + lane] = taop[0] * acc;
}

// ---------------------------------------------------------------------------
extern "C" void kernel_launch(void* const* d_in, const int* in_sizes, int n_in,
                              void* d_out, int out_size, void* d_ws, size_t ws_size,
                              hipStream_t stream) {
  const float* x   = (const float*)d_in[0];
  const float* tao = (const float*)d_in[1];
  float* out = (float*)d_out;

  // workspace layout (floats), total ~14 MB
  float* qn     = (float*)d_ws;                       // 8192*128
  float* pkv    = qn + (size_t)M * D;                 // 8192*16*9
  int*   pki    = (int*)(pkv + (size_t)M * NPART * KTOP);
  float* kval   = (float*)(pki + (size_t)M * NPART * KTOP);  // 8192*9
  int*   kidx   = (int*)(kval + (size_t)M * KTOP);
  float* protnT = (float*)(kidx + (size_t)M * KTOP);  // 128*64

  k0_proto<<<NCLS, 64, 0, stream>>>(x, protnT);
  k1_qnorm<<<M / 4, 256, 0, stream>>>(x, qn);
  k2_topk<<<(M / IB) * SJ2, TPB2, 0, stream>>>(qn, pkv, pki);
  k_merge<<<M / 256, 256, 0, stream>>>(pkv, pki, kval, kidx);
  k3_out<<<M / 4, 256, 0, stream>>>(x, kval, kidx, protnT, tao, out);
}

// Round 6
// 14668.895 us; speedup vs baseline: 1.0000x; 1.0000x over previous
//
#include <hip/hip_runtime.h>
#include <hip/hip_bf16.h>
#include <math.h>

// Problem constants (N_WAY=64, K_SHOT=5, Q_QUERY=128, D_FEAT=128)
#define M     8192      // n*q query rows
#define D     128       // feature dim
#define NCLS  64        // n classes
#define KSHOT 5
#define XROW  133       // (k+q) rows per class in x
#define KTOP  9
#define EPSV  1e-8f

// k2 config: 64 i-rows/block (one per LANE, shared by all 8 waves),
// 2 j-splits, j-tiles of 64 rows double-buffered in LDS.
#define IB    64
#define W2    8
#define TPB2  (W2 * 64)     // 512
#define SJ2   2
#define TJ    64            // j rows per LDS tile
#define JPB   (M / SJ2)     // 4096 j per block
#define NTILE (JPB / TJ)    // 64 tiles
#define JW    8             // j rows per wave per tile
#define NPART (SJ2 * W2)    // 16 partial top-9 lists per i-row

// ---------------------------------------------------------------------------
// register-resident top-9 with (value desc, index asc) tie-break, matching
// jax.lax.top_k set semantics. Fully unrolled -> static indexing -> VGPRs.
__device__ __forceinline__ void top9_insert(float (&kv)[KTOP], int (&ki)[KTOP],
                                            float v, int j) {
  if (v > kv[KTOP - 1] || (v == kv[KTOP - 1] && j < ki[KTOP - 1])) {
    float cv = v; int cj = j;
#pragma unroll
    for (int t = 0; t < KTOP; ++t) {
      bool b = (cv > kv[t]) || (cv == kv[t] && cj < ki[t]);
      float tv = kv[t]; int ti = ki[t];
      kv[t] = b ? cv : tv;  ki[t] = b ? cj : ti;
      cv   = b ? tv : cv;   cj   = b ? ti : cj;
    }
  }
}

// ---------------------------------------------------------------------------
// k0: class prototypes = mean of 5 support rows, L2-normalized, stored
// TRANSPOSED protnT[d][c] so k3's per-lane-class reads are coalesced.
__global__ void k0_proto(const float* __restrict__ x, float* __restrict__ protnT) {
  int c = blockIdx.x;
  int lane = threadIdx.x;
  const float* base = x + (size_t)(c * XROW) * D;
  float a0 = 0.f, a1 = 0.f;
#pragma unroll
  for (int s = 0; s < KSHOT; ++s) {
    a0 += base[s * D + lane];
    a1 += base[s * D + 64 + lane];
  }
  a0 *= 0.2f; a1 *= 0.2f;
  float ss = a0 * a0 + a1 * a1;
#pragma unroll
  for (int off = 1; off < 64; off <<= 1) ss += __shfl_xor(ss, off);
  float rn = 1.0f / fmaxf(sqrtf(ss), EPSV);
  protnT[lane * NCLS + c]        = a0 * rn;
  protnT[(lane + 64) * NCLS + c] = a1 * rn;
}

// ---------------------------------------------------------------------------
// k1: L2-normalize the 8192 query rows into qn (row-major, 4 MB).
__global__ void k1_qnorm(const float* __restrict__ x, float* __restrict__ qn) {
  int lane = threadIdx.x & 63;
  int wv = threadIdx.x >> 6;
  int r = blockIdx.x * 4 + wv;
  int xr = (r >> 7) * XROW + KSHOT + (r & 127);
  const float* src = x + (size_t)xr * D;
  float v0 = src[lane], v1 = src[64 + lane];
  float ss = v0 * v0 + v1 * v1;
#pragma unroll
  for (int off = 1; off < 64; off <<= 1) ss += __shfl_xor(ss, off);
  float rn = 1.0f / fmaxf(sqrtf(ss), EPSV);
  qn[(size_t)r * D + lane]      = v0 * rn;
  qn[(size_t)r * D + 64 + lane] = v1 * rn;
}

// ---------------------------------------------------------------------------
// async 16B global -> LDS (contiguous slab copy, coalesced, no VGPR roundtrip)
__device__ __forceinline__ void stage_tile(const float* __restrict__ src,
                                           float* dst, int tid) {
#pragma unroll
  for (int k = 0; k < 4; ++k) {
    int flat = k * TPB2 + tid;          // float4 index; lds = uniform + lane*16
    __builtin_amdgcn_global_load_lds(
        (const __attribute__((address_space(1))) void*)(src + (size_t)flat * 4),
        (__attribute__((address_space(3))) void*)(dst + (size_t)flat * 4),
        16, 0, 0);
  }
}

// ---------------------------------------------------------------------------
// k2: heavy pass. Lane's own qn row lives in 32 float4 REGISTERS (no a-loads).
// j-tile (64 rows, 32 KB, contiguous in qn) double-buffered in LDS via
// global_load_lds; in-loop B reads are wave-uniform ds_read_b128 (broadcast,
// conflict-free). Per chunk: 8 ds_read + 32 v_fma -> VALU-bound.
//
// __launch_bounds__(512, 1): 1 block/CU -> 2 waves/SIMD -> VGPR cap 256.
// R2's (512,2) capped VGPRs at 128 (2 blocks/CU semantics) and spilled
// areg+acc to scratch: 40 GB/dispatch HBM traffic, 14.7 ms. Need ~200 VGPRs.
__global__ __launch_bounds__(TPB2, 1) void
k2_topk(const float* __restrict__ qn, float* __restrict__ pkv, int* __restrict__ pki) {
  __shared__ float Bs[2][TJ * D];       // 2 x 32 KB

  const int tid  = threadIdx.x;
  const int lane = tid & 63;
  const int wv   = tid >> 6;
  const int ib   = blockIdx.x >> 1;     // 128 i-blocks
  const int js   = blockIdx.x & 1;      // 2 j-splits
  const int i    = ib * IB + lane;
  const int jbase0 = js * JPB;

  // own (normalized) query row -> registers, statically indexed
  float4 areg[32];
  {
    const float4* arow = (const float4*)(qn + (size_t)i * D);
#pragma unroll
    for (int c = 0; c < 32; ++c) areg[c] = arow[c];
  }

  float kv[KTOP]; int ki[KTOP];
#pragma unroll
  for (int t = 0; t < KTOP; ++t) { kv[t] = -INFINITY; ki[t] = 0x7fffffff; }

  // prologue: stage tile 0
  stage_tile(qn + (size_t)jbase0 * D, Bs[0], tid);
  asm volatile("s_waitcnt vmcnt(0)" ::: "memory");
  __syncthreads();

  for (int t = 0; t < NTILE; ++t) {
    const int cur = t & 1;
    if (t + 1 < NTILE)
      stage_tile(qn + (size_t)(jbase0 + (t + 1) * TJ) * D, Bs[cur ^ 1], tid);

    const float4* bb = (const float4*)(Bs[cur] + (size_t)(wv * JW) * D);
    float acc[JW];
#pragma unroll
    for (int u = 0; u < JW; ++u) acc[u] = 0.f;

#pragma unroll
    for (int c = 0; c < 32; ++c) {
      float4 a = areg[c];
#pragma unroll
      for (int u = 0; u < JW; ++u) {
        float4 b = bb[u * 32 + c];      // wave-uniform broadcast ds_read_b128
        acc[u] += a.x * b.x + a.y * b.y + a.z * b.z + a.w * b.w;
      }
    }

    const int j0 = jbase0 + t * TJ + wv * JW;
#pragma unroll
    for (int u = 0; u < JW; ++u) top9_insert(kv, ki, acc[u], j0 + u);

    asm volatile("s_waitcnt vmcnt(0)" ::: "memory");   // staging loads landed
    __syncthreads();                                   // all waves done reading
  }

  const int p = js * W2 + wv;
  size_t base = ((size_t)i * NPART + p) * KTOP;
#pragma unroll
  for (int t = 0; t < KTOP; ++t) { pkv[base + t] = kv[t]; pki[base + t] = ki[t]; }
}

// ---------------------------------------------------------------------------
// k_merge: per row, merge the 16 partial top-9 lists (disjoint j-ranges).
__global__ void k_merge(const float* __restrict__ pkv, const int* __restrict__ pki,
                        float* __restrict__ kval, int* __restrict__ kidx) {
  int i = blockIdx.x * blockDim.x + threadIdx.x;
  float kv[KTOP]; int ki[KTOP];
#pragma unroll
  for (int t = 0; t < KTOP; ++t) { kv[t] = -INFINITY; ki[t] = 0x7fffffff; }
  const float* pv = pkv + (size_t)i * NPART * KTOP;
  const int*   pi = pki + (size_t)i * NPART * KTOP;
  for (int t = 0; t < NPART * KTOP; ++t) top9_insert(kv, ki, pv[t], pi[t]);
#pragma unroll
  for (int t = 0; t < KTOP; ++t) {
    kval[(size_t)i * KTOP + t] = kv[t];
    kidx[(size_t)i * KTOP + t] = ki[t];
  }
}

// ---------------------------------------------------------------------------
// k3: mutual mask + softmax over <=9 entries + adapted query + normalize +
// project on normalized prototypes, scale by tao. One wave per query row.
__global__ void k3_out(const float* __restrict__ x, const float* __restrict__ kval,
                       const int* __restrict__ kidx, const float* __restrict__ protnT,
                       const float* __restrict__ taop, float* __restrict__ out) {
  __shared__ float sw[4][KTOP];
  __shared__ int   sj[4][KTOP];
  __shared__ float an[4][D];
  int lane = threadIdx.x & 63;
  int wv   = threadIdx.x >> 6;
  int i = blockIdx.x * 4 + wv;

  float v = -INFINITY; int jt = 0; bool mut = false;
  if (lane < KTOP) {
    v  = kval[(size_t)i * KTOP + lane];
    jt = kidx[(size_t)i * KTOP + lane];
    const int* oj = kidx + (size_t)jt * KTOP;
#pragma unroll
    for (int t = 0; t < KTOP; ++t) mut = mut || (oj[t] == i);
  }
  float lv = mut ? v : -INFINITY;
#pragma unroll
  for (int off = 1; off < 16; off <<= 1) lv = fmaxf(lv, __shfl_xor(lv, off));
  float wexp = mut ? expf(v - lv) : 0.f;    // self is always mutual -> z >= 1
  float z = wexp;
#pragma unroll
  for (int off = 1; off < 16; off <<= 1) z += __shfl_xor(z, off);
  if (lane < KTOP) { sw[wv][lane] = wexp / z; sj[wv][lane] = jt; }
  __syncthreads();

  float a0 = 0.f, a1 = 0.f;
#pragma unroll
  for (int t = 0; t < KTOP; ++t) {
    float wt = sw[wv][t];
    if (wt != 0.f) {
      int j = sj[wv][t];
      int xr = (j >> 7) * XROW + KSHOT + (j & 127);
      const float* qr = x + (size_t)xr * D;
      a0 += wt * qr[lane];
      a1 += wt * qr[64 + lane];
    }
  }
  float ss = a0 * a0 + a1 * a1;
#pragma unroll
  for (int off = 1; off < 64; off <<= 1) ss += __shfl_xor(ss, off);
  float rn = 1.0f / fmaxf(sqrtf(ss), EPSV);
  an[wv][lane]      = a0 * rn;
  an[wv][64 + lane] = a1 * rn;
  __syncthreads();

  float acc = 0.f;
#pragma unroll 8
  for (int d = 0; d < D; ++d) acc += an[wv][d] * protnT[d * NCLS + lane];
  out[(size_t)i * NCLS + lane] = taop[0] * acc;
}

// ---------------------------------------------------------------------------
extern "C" void kernel_launch(void* const* d_in, const int* in_sizes, int n_in,
                              void* d_out, int out_size, void* d_ws, size_t ws_size,
                              hipStream_t stream) {
  const float* x   = (const float*)d_in[0];
  const float* tao = (const float*)d_in[1];
  float* out = (float*)d_out;

  // workspace layout (floats), total ~14 MB
  float* qn     = (float*)d_ws;                       // 8192*128
  float* pkv    = qn + (size_t)M * D;                 // 8192*16*9
  int*   pki    = (int*)(pkv + (size_t)M * NPART * KTOP);
  float* kval   = (float*)(pki + (size_t)M * NPART * KTOP);  // 8192*9
  int*   kidx   = (int*)(kval + (size_t)M * KTOP);
  float* protnT = (float*)(kidx + (size_t)M * KTOP);  // 128*64

  k0_proto<<<NCLS, 64, 0, stream>>>(x, protnT);
  k1_qnorm<<<M / 4, 256, 0, stream>>>(x, qn);
  k2_topk<<<(M / IB) * SJ2, TPB2, 0, stream>>>(qn, pkv, pki);
  k_merge<<<M / 256, 256, 0, stream>>>(pkv, pki, kval, kidx);
  k3_out<<<M / 4, 256, 0, stream>>>(x, kval, kidx, protnT, tao, out);
}

// Round 7
// 14666.951 us; speedup vs baseline: 1.0001x; 1.0001x over previous
//
#include <hip/hip_runtime.h>
#include <hip/hip_bf16.h>
#include <math.h>

// Problem constants (N_WAY=64, K_SHOT=5, Q_QUERY=128, D_FEAT=128)
#define M     8192      // n*q query rows
#define D     128       // feature dim
#define NCLS  64        // n classes
#define KSHOT 5
#define XROW  133       // (k+q) rows per class in x
#define KTOP  9
#define EPSV  1e-8f

// k2 config: 64 i-rows/block (one per LANE, shared by all 8 waves),
// 2 j-splits, j-tiles of 64 rows double-buffered in LDS.
#define IB    64
#define W2    8
#define TPB2  (W2 * 64)     // 512
#define SJ2   2
#define TJ    64            // j rows per LDS tile
#define JPB   (M / SJ2)     // 4096 j per block
#define NTILE (JPB / TJ)    // 64 tiles
#define JW    8             // j rows per wave per tile
#define NPART (SJ2 * W2)    // 16 partial top-9 lists per i-row
// LDS buffer stride: tile (32 KB) + 10 KB pad -> 2 buffers = 84 KB > 80 KB,
// so only ONE block/CU fits by LDS. The AMDGPU backend derives its occupancy
// target (and thus the VGPR cap) from LDS: at 64 KB it targeted 2 blocks/CU
// = 4 waves/SIMD = 128-VGPR cap and spilled areg+acc (40 GB scratch, 14.7ms).
// 84 KB -> 2 waves/SIMD -> 256-VGPR cap. amdgpu_waves_per_eu(2,2) says the
// same thing explicitly.
#define BSTRIDE (TJ * D + 2560)

// ---------------------------------------------------------------------------
// register-resident top-9 with (value desc, index asc) tie-break, matching
// jax.lax.top_k set semantics. Fully unrolled -> static indexing -> VGPRs.
__device__ __forceinline__ void top9_insert(float (&kv)[KTOP], int (&ki)[KTOP],
                                            float v, int j) {
  if (v > kv[KTOP - 1] || (v == kv[KTOP - 1] && j < ki[KTOP - 1])) {
    float cv = v; int cj = j;
#pragma unroll
    for (int t = 0; t < KTOP; ++t) {
      bool b = (cv > kv[t]) || (cv == kv[t] && cj < ki[t]);
      float tv = kv[t]; int ti = ki[t];
      kv[t] = b ? cv : tv;  ki[t] = b ? cj : ti;
      cv   = b ? tv : cv;   cj   = b ? ti : cj;
    }
  }
}

// ---------------------------------------------------------------------------
// k0: class prototypes = mean of 5 support rows, L2-normalized, stored
// TRANSPOSED protnT[d][c] so k3's per-lane-class reads are coalesced.
__global__ void k0_proto(const float* __restrict__ x, float* __restrict__ protnT) {
  int c = blockIdx.x;
  int lane = threadIdx.x;
  const float* base = x + (size_t)(c * XROW) * D;
  float a0 = 0.f, a1 = 0.f;
#pragma unroll
  for (int s = 0; s < KSHOT; ++s) {
    a0 += base[s * D + lane];
    a1 += base[s * D + 64 + lane];
  }
  a0 *= 0.2f; a1 *= 0.2f;
  float ss = a0 * a0 + a1 * a1;
#pragma unroll
  for (int off = 1; off < 64; off <<= 1) ss += __shfl_xor(ss, off);
  float rn = 1.0f / fmaxf(sqrtf(ss), EPSV);
  protnT[lane * NCLS + c]        = a0 * rn;
  protnT[(lane + 64) * NCLS + c] = a1 * rn;
}

// ---------------------------------------------------------------------------
// k1: L2-normalize the 8192 query rows into qn (row-major, 4 MB).
__global__ void k1_qnorm(const float* __restrict__ x, float* __restrict__ qn) {
  int lane = threadIdx.x & 63;
  int wv = threadIdx.x >> 6;
  int r = blockIdx.x * 4 + wv;
  int xr = (r >> 7) * XROW + KSHOT + (r & 127);
  const float* src = x + (size_t)xr * D;
  float v0 = src[lane], v1 = src[64 + lane];
  float ss = v0 * v0 + v1 * v1;
#pragma unroll
  for (int off = 1; off < 64; off <<= 1) ss += __shfl_xor(ss, off);
  float rn = 1.0f / fmaxf(sqrtf(ss), EPSV);
  qn[(size_t)r * D + lane]      = v0 * rn;
  qn[(size_t)r * D + 64 + lane] = v1 * rn;
}

// ---------------------------------------------------------------------------
// async 16B global -> LDS (contiguous slab copy, coalesced, no VGPR roundtrip)
__device__ __forceinline__ void stage_tile(const float* __restrict__ src,
                                           float* dst, int tid) {
#pragma unroll
  for (int k = 0; k < 4; ++k) {
    int flat = k * TPB2 + tid;          // float4 index; lds = uniform + lane*16
    __builtin_amdgcn_global_load_lds(
        (const __attribute__((address_space(1))) void*)(src + (size_t)flat * 4),
        (__attribute__((address_space(3))) void*)(dst + (size_t)flat * 4),
        16, 0, 0);
  }
}

// ---------------------------------------------------------------------------
// k2: heavy pass. Lane's own qn row lives in 32 float4 REGISTERS (no a-loads).
// j-tile (64 rows, 32 KB, contiguous in qn) double-buffered in LDS via
// global_load_lds; in-loop B reads are wave-uniform ds_read_b128 (broadcast,
// conflict-free). Per chunk: 8 ds_read + 32 v_fma -> VALU-bound.
__global__ __attribute__((amdgpu_waves_per_eu(2, 2))) __launch_bounds__(TPB2) void
k2_topk(const float* __restrict__ qn, float* __restrict__ pkv, int* __restrict__ pki) {
  __shared__ float Bs[2 * BSTRIDE];     // 2 x (32 KB + 10 KB pad) = 84 KB

  const int tid  = threadIdx.x;
  const int lane = tid & 63;
  const int wv   = tid >> 6;
  const int ib   = blockIdx.x >> 1;     // 128 i-blocks
  const int js   = blockIdx.x & 1;      // 2 j-splits
  const int i    = ib * IB + lane;
  const int jbase0 = js * JPB;

  // own (normalized) query row -> registers, statically indexed
  float4 areg[32];
  {
    const float4* arow = (const float4*)(qn + (size_t)i * D);
#pragma unroll
    for (int c = 0; c < 32; ++c) areg[c] = arow[c];
  }

  float kv[KTOP]; int ki[KTOP];
#pragma unroll
  for (int t = 0; t < KTOP; ++t) { kv[t] = -INFINITY; ki[t] = 0x7fffffff; }

  // prologue: stage tile 0
  stage_tile(qn + (size_t)jbase0 * D, &Bs[0], tid);
  asm volatile("s_waitcnt vmcnt(0)" ::: "memory");
  __syncthreads();

  for (int t = 0; t < NTILE; ++t) {
    const int cur = t & 1;
    if (t + 1 < NTILE)
      stage_tile(qn + (size_t)(jbase0 + (t + 1) * TJ) * D,
                 &Bs[(cur ^ 1) * BSTRIDE], tid);

    const float4* bb = (const float4*)(&Bs[cur * BSTRIDE] + (size_t)(wv * JW) * D);
    float acc[JW];
#pragma unroll
    for (int u = 0; u < JW; ++u) acc[u] = 0.f;

#pragma unroll
    for (int c = 0; c < 32; ++c) {
      float4 a = areg[c];
#pragma unroll
      for (int u = 0; u < JW; ++u) {
        float4 b = bb[u * 32 + c];      // wave-uniform broadcast ds_read_b128
        acc[u] += a.x * b.x + a.y * b.y + a.z * b.z + a.w * b.w;
      }
    }

    const int j0 = jbase0 + t * TJ + wv * JW;
#pragma unroll
    for (int u = 0; u < JW; ++u) top9_insert(kv, ki, acc[u], j0 + u);

    asm volatile("s_waitcnt vmcnt(0)" ::: "memory");   // staging loads landed
    __syncthreads();                                   // all waves done reading
  }

  const int p = js * W2 + wv;
  size_t base = ((size_t)i * NPART + p) * KTOP;
#pragma unroll
  for (int t = 0; t < KTOP; ++t) { pkv[base + t] = kv[t]; pki[base + t] = ki[t]; }
}

// ---------------------------------------------------------------------------
// k_merge: per row, merge the 16 partial top-9 lists (disjoint j-ranges).
__global__ void k_merge(const float* __restrict__ pkv, const int* __restrict__ pki,
                        float* __restrict__ kval, int* __restrict__ kidx) {
  int i = blockIdx.x * blockDim.x + threadIdx.x;
  float kv[KTOP]; int ki[KTOP];
#pragma unroll
  for (int t = 0; t < KTOP; ++t) { kv[t] = -INFINITY; ki[t] = 0x7fffffff; }
  const float* pv = pkv + (size_t)i * NPART * KTOP;
  const int*   pi = pki + (size_t)i * NPART * KTOP;
  for (int t = 0; t < NPART * KTOP; ++t) top9_insert(kv, ki, pv[t], pi[t]);
#pragma unroll
  for (int t = 0; t < KTOP; ++t) {
    kval[(size_t)i * KTOP + t] = kv[t];
    kidx[(size_t)i * KTOP + t] = ki[t];
  }
}

// ---------------------------------------------------------------------------
// k3: mutual mask + softmax over <=9 entries + adapted query + normalize +
// project on normalized prototypes, scale by tao. One wave per query row.
__global__ void k3_out(const float* __restrict__ x, const float* __restrict__ kval,
                       const int* __restrict__ kidx, const float* __restrict__ protnT,
                       const float* __restrict__ taop, float* __restrict__ out) {
  __shared__ float sw[4][KTOP];
  __shared__ int   sj[4][KTOP];
  __shared__ float an[4][D];
  int lane = threadIdx.x & 63;
  int wv   = threadIdx.x >> 6;
  int i = blockIdx.x * 4 + wv;

  float v = -INFINITY; int jt = 0; bool mut = false;
  if (lane < KTOP) {
    v  = kval[(size_t)i * KTOP + lane];
    jt = kidx[(size_t)i * KTOP + lane];
    const int* oj = kidx + (size_t)jt * KTOP;
#pragma unroll
    for (int t = 0; t < KTOP; ++t) mut = mut || (oj[t] == i);
  }
  float lv = mut ? v : -INFINITY;
#pragma unroll
  for (int off = 1; off < 16; off <<= 1) lv = fmaxf(lv, __shfl_xor(lv, off));
  float wexp = mut ? expf(v - lv) : 0.f;    // self is always mutual -> z >= 1
  float z = wexp;
#pragma unroll
  for (int off = 1; off < 16; off <<= 1) z += __shfl_xor(z, off);
  if (lane < KTOP) { sw[wv][lane] = wexp / z; sj[wv][lane] = jt; }
  __syncthreads();

  float a0 = 0.f, a1 = 0.f;
#pragma unroll
  for (int t = 0; t < KTOP; ++t) {
    float wt = sw[wv][t];
    if (wt != 0.f) {
      int j = sj[wv][t];
      int xr = (j >> 7) * XROW + KSHOT + (j & 127);
      const float* qr = x + (size_t)xr * D;
      a0 += wt * qr[lane];
      a1 += wt * qr[64 + lane];
    }
  }
  float ss = a0 * a0 + a1 * a1;
#pragma unroll
  for (int off = 1; off < 64; off <<= 1) ss += __shfl_xor(ss, off);
  float rn = 1.0f / fmaxf(sqrtf(ss), EPSV);
  an[wv][lane]      = a0 * rn;
  an[wv][64 + lane] = a1 * rn;
  __syncthreads();

  float acc = 0.f;
#pragma unroll 8
  for (int d = 0; d < D; ++d) acc += an[wv][d] * protnT[d * NCLS + lane];
  out[(size_t)i * NCLS + lane] = taop[0] * acc;
}

// ---------------------------------------------------------------------------
extern "C" void kernel_launch(void* const* d_in, const int* in_sizes, int n_in,
                              void* d_out, int out_size, void* d_ws, size_t ws_size,
                              hipStream_t stream) {
  const float* x   = (const float*)d_in[0];
  const float* tao = (const float*)d_in[1];
  float* out = (float*)d_out;

  // workspace layout (floats), total ~14 MB
  float* qn     = (float*)d_ws;                       // 8192*128
  float* pkv    = qn + (size_t)M * D;                 // 8192*16*9
  int*   pki    = (int*)(pkv + (size_t)M * NPART * KTOP);
  float* kval   = (float*)(pki + (size_t)M * NPART * KTOP);  // 8192*9
  int*   kidx   = (int*)(kval + (size_t)M * KTOP);
  float* protnT = (float*)(kidx + (size_t)M * KTOP);  // 128*64

  k0_proto<<<NCLS, 64, 0, stream>>>(x, protnT);
  k1_qnorm<<<M / 4, 256, 0, stream>>>(x, qn);
  k2_topk<<<(M / IB) * SJ2, TPB2, 0, stream>>>(qn, pkv, pki);
  k_merge<<<M / 256, 256, 0, stream>>>(pkv, pki, kval, kidx);
  k3_out<<<M / 4, 256, 0, stream>>>(x, kval, kidx, protnT, tao, out);
}

// Round 8
// 552.364 us; speedup vs baseline: 26.5569x; 26.5530x over previous
//
#include <hip/hip_runtime.h>
#include <hip/hip_bf16.h>
#include <math.h>

// Problem constants (N_WAY=64, K_SHOT=5, Q_QUERY=128, D_FEAT=128)
#define M     8192      // n*q query rows
#define D     128       // feature dim
#define NCLS  64        // n classes
#define KSHOT 5
#define XROW  133       // (k+q) rows per class in x
#define KTOP  9
#define EPSV  1e-8f

// k2: 256 thr, 64 i-rows/block, 4x4 acc per thread, 64-j tiles, SJ=4 j-splits.
// LDS 64KB -> 2 blocks/CU. VGPR ~95 -> fits the 128 budget (R2-R6 lesson:
// the compiler will NOT exceed 128 VGPRs for this kernel shape; the 32-float4
// A-row-in-registers design spilled 40 GB/dispatch to scratch. Design under it.)
#define TPB   256
#define IB    64
#define SJ    4
#define JPB   (M / SJ)      // 2048 j per block
#define TJ    64            // j rows per tile
#define NT    (JPB / TJ)    // 32 tiles
#define NQ    4             // j-quarter scanners per row
#define NPART (SJ * NQ)     // 16 partial top-9 lists per i-row
#define SIMLD 68            // sim row stride (floats): 16B-aligned, bank-spread

// ---------------------------------------------------------------------------
// register-resident top-9 with (value desc, index asc) tie-break, matching
// jax.lax.top_k set semantics. Fully unrolled -> static indexing -> VGPRs.
__device__ __forceinline__ void top9_insert(float (&kv)[KTOP], int (&ki)[KTOP],
                                            float v, int j) {
  if (v > kv[KTOP - 1] || (v == kv[KTOP - 1] && j < ki[KTOP - 1])) {
    float cv = v; int cj = j;
#pragma unroll
    for (int t = 0; t < KTOP; ++t) {
      bool b = (cv > kv[t]) || (cv == kv[t] && cj < ki[t]);
      float tv = kv[t]; int ti_ = ki[t];
      kv[t] = b ? cv : tv;  ki[t] = b ? cj : ti_;
      cv   = b ? tv : cv;   cj   = b ? ti_ : cj;
    }
  }
}

// ---------------------------------------------------------------------------
__global__ void k0_proto(const float* __restrict__ x, float* __restrict__ protnT) {
  int c = blockIdx.x;
  int lane = threadIdx.x;
  const float* base = x + (size_t)(c * XROW) * D;
  float a0 = 0.f, a1 = 0.f;
#pragma unroll
  for (int s = 0; s < KSHOT; ++s) {
    a0 += base[s * D + lane];
    a1 += base[s * D + 64 + lane];
  }
  a0 *= 0.2f; a1 *= 0.2f;
  float ss = a0 * a0 + a1 * a1;
#pragma unroll
  for (int off = 1; off < 64; off <<= 1) ss += __shfl_xor(ss, off);
  float rn = 1.0f / fmaxf(sqrtf(ss), EPSV);
  protnT[lane * NCLS + c]        = a0 * rn;
  protnT[(lane + 64) * NCLS + c] = a1 * rn;
}

// ---------------------------------------------------------------------------
__global__ void k1_qnorm(const float* __restrict__ x, float* __restrict__ qn) {
  int lane = threadIdx.x & 63;
  int wv = threadIdx.x >> 6;
  int r = blockIdx.x * 4 + wv;
  int xr = (r >> 7) * XROW + KSHOT + (r & 127);
  const float* src = x + (size_t)xr * D;
  float v0 = src[lane], v1 = src[64 + lane];
  float ss = v0 * v0 + v1 * v1;
#pragma unroll
  for (int off = 1; off < 64; off <<= 1) ss += __shfl_xor(ss, off);
  float rn = 1.0f / fmaxf(sqrtf(ss), EPSV);
  qn[(size_t)r * D + lane]      = v0 * rn;
  qn[(size_t)r * D + 64 + lane] = v1 * rn;
}

// ---------------------------------------------------------------------------
// k2: 64i x 64j tiles. At[k][i], Bt[k][j] transposed in LDS; per k each thread
// does 2 ds_read_b128 + 16 v_fma (8:1 FMA:LDS). After each tile, acc is staged
// into sim[64][68] (aliasing the dead Bt region) and each thread top9-scans
// one row-quarter. B tile t+1 is global-loaded to regs BEFORE compute(t)
// (latency hidden under 4096 FMA cycles) and LDS-written after the scan.
__global__ __launch_bounds__(TPB) void
k2_topk(const float* __restrict__ qn, float* __restrict__ pkv, int* __restrict__ pki) {
  __shared__ float At[128 * 64];            // 32 KB, staged once
  __shared__ float Bt[128 * 64];            // 32 KB, re-staged per tile; sim alias
  float* sim = Bt;                          // sim[64][SIMLD] <= 17.4 KB < 32 KB

  const int tid  = threadIdx.x;
  const int ib   = blockIdx.x >> 2;         // 128 i-blocks
  const int js   = blockIdx.x & (SJ - 1);   // 4 j-splits
  const int ibase = ib * IB;
  const int jbase = js * JPB;

  const int ti  = tid & 15;                 // i-group (4 rows)
  const int tj  = tid >> 4;                 // j-group (4 cols), 0..15
  const int sr  = tid & 63;                 // scan row
  const int sq  = tid >> 6;                 // scan j-quarter, 0..3
  const int br  = tid >> 2;                 // B-stage row, 0..63
  const int bkq = tid & 3;                  // B-stage k-quarter

  // ---- stage A transposed (once): thread handles (row sr, k-quarter sq) ----
  {
    const float4* src = (const float4*)(qn + (size_t)(ibase + sr) * D + sq * 32);
#pragma unroll
    for (int f = 0; f < 8; ++f) {
      float4 v = src[f];
      int k0 = sq * 32 + f * 4;
      At[(k0 + 0) * 64 + sr] = v.x;
      At[(k0 + 1) * 64 + sr] = v.y;
      At[(k0 + 2) * 64 + sr] = v.z;
      At[(k0 + 3) * 64 + sr] = v.w;
    }
  }

  // ---- stage B tile 0: global -> regs -> LDS transposed ----
  float4 breg[8];
  {
    const float4* src = (const float4*)(qn + (size_t)(jbase + br) * D + bkq * 32);
#pragma unroll
    for (int f = 0; f < 8; ++f) breg[f] = src[f];
#pragma unroll
    for (int f = 0; f < 8; ++f) {
      int k0 = bkq * 32 + f * 4;
      Bt[(k0 + 0) * 64 + br] = breg[f].x;
      Bt[(k0 + 1) * 64 + br] = breg[f].y;
      Bt[(k0 + 2) * 64 + br] = breg[f].z;
      Bt[(k0 + 3) * 64 + br] = breg[f].w;
    }
  }
  __syncthreads();

  float kv[KTOP]; int ki[KTOP];
#pragma unroll
  for (int t = 0; t < KTOP; ++t) { kv[t] = -INFINITY; ki[t] = 0x7fffffff; }

  for (int t = 0; t < NT; ++t) {
    // issue next tile's global loads now; they complete under the FMA loop
    if (t + 1 < NT) {
      const float4* src =
          (const float4*)(qn + (size_t)(jbase + (t + 1) * TJ + br) * D + bkq * 32);
#pragma unroll
      for (int f = 0; f < 8; ++f) breg[f] = src[f];
    }

    // ---- 64x64x128 tile GEMM: 4x4 acc per thread ----
    float acc[16];
#pragma unroll
    for (int u = 0; u < 16; ++u) acc[u] = 0.f;
    const float* ap = At + ti * 4;
    const float* bp = Bt + tj * 4;
#pragma unroll 4
    for (int k = 0; k < 128; ++k) {
      float4 a = *(const float4*)(ap + k * 64);
      float4 b = *(const float4*)(bp + k * 64);
      acc[0]  += a.x * b.x; acc[1]  += a.x * b.y; acc[2]  += a.x * b.z; acc[3]  += a.x * b.w;
      acc[4]  += a.y * b.x; acc[5]  += a.y * b.y; acc[6]  += a.y * b.z; acc[7]  += a.y * b.w;
      acc[8]  += a.z * b.x; acc[9]  += a.z * b.y; acc[10] += a.z * b.z; acc[11] += a.z * b.w;
      acc[12] += a.w * b.x; acc[13] += a.w * b.y; acc[14] += a.w * b.z; acc[15] += a.w * b.w;
    }
    __syncthreads();                          // everyone done reading Bt

    // ---- acc -> sim (aliases Bt; tile data now dead) ----
#pragma unroll
    for (int r = 0; r < 4; ++r) {
      float4 v = make_float4(acc[r * 4 + 0], acc[r * 4 + 1],
                             acc[r * 4 + 2], acc[r * 4 + 3]);
      *(float4*)(sim + (size_t)(ti * 4 + r) * SIMLD + tj * 4) = v;
    }
    __syncthreads();

    // ---- top9 scan: thread scans row sr, cols [sq*16, sq*16+16) ----
    {
      const float* srow = sim + (size_t)sr * SIMLD + sq * 16;
      int j0 = jbase + t * TJ + sq * 16;
#pragma unroll
      for (int m = 0; m < 4; ++m) {
        float4 v = *(const float4*)(srow + m * 4);
        top9_insert(kv, ki, v.x, j0 + m * 4 + 0);
        top9_insert(kv, ki, v.y, j0 + m * 4 + 1);
        top9_insert(kv, ki, v.z, j0 + m * 4 + 2);
        top9_insert(kv, ki, v.w, j0 + m * 4 + 3);
      }
    }
    __syncthreads();                          // scan done before Bt overwrite

    // ---- write B tile t+1 (overwrites sim region) ----
    if (t + 1 < NT) {
#pragma unroll
      for (int f = 0; f < 8; ++f) {
        int k0 = bkq * 32 + f * 4;
        Bt[(k0 + 0) * 64 + br] = breg[f].x;
        Bt[(k0 + 1) * 64 + br] = breg[f].y;
        Bt[(k0 + 2) * 64 + br] = breg[f].z;
        Bt[(k0 + 3) * 64 + br] = breg[f].w;
      }
    }
    __syncthreads();
  }

  // ---- write partial top-9 list: (row sr, part js*NQ+sq) ----
  {
    int i = ibase + sr;
    int p = js * NQ + sq;
    size_t base = ((size_t)i * NPART + p) * KTOP;
#pragma unroll
    for (int t = 0; t < KTOP; ++t) { pkv[base + t] = kv[t]; pki[base + t] = ki[t]; }
  }
}

// ---------------------------------------------------------------------------
// k_merge: per row, merge the 16 partial top-9 lists (disjoint j-ranges).
__global__ void k_merge(const float* __restrict__ pkv, const int* __restrict__ pki,
                        float* __restrict__ kval, int* __restrict__ kidx) {
  int i = blockIdx.x * blockDim.x + threadIdx.x;
  float kv[KTOP]; int ki[KTOP];
#pragma unroll
  for (int t = 0; t < KTOP; ++t) { kv[t] = -INFINITY; ki[t] = 0x7fffffff; }
  const float* pv = pkv + (size_t)i * NPART * KTOP;
  const int*   pi = pki + (size_t)i * NPART * KTOP;
  for (int t = 0; t < NPART * KTOP; ++t) top9_insert(kv, ki, pv[t], pi[t]);
#pragma unroll
  for (int t = 0; t < KTOP; ++t) {
    kval[(size_t)i * KTOP + t] = kv[t];
    kidx[(size_t)i * KTOP + t] = ki[t];
  }
}

// ---------------------------------------------------------------------------
// k3: mutual mask + softmax over <=9 entries + adapted query + normalize +
// project on normalized prototypes, scale by tao. One wave per query row.
__global__ void k3_out(const float* __restrict__ x, const float* __restrict__ kval,
                       const int* __restrict__ kidx, const float* __restrict__ protnT,
                       const float* __restrict__ taop, float* __restrict__ out) {
  __shared__ float sw[4][KTOP];
  __shared__ int   sj[4][KTOP];
  __shared__ float an[4][D];
  int lane = threadIdx.x & 63;
  int wv   = threadIdx.x >> 6;
  int i = blockIdx.x * 4 + wv;

  float v = -INFINITY; int jt = 0; bool mut = false;
  if (lane < KTOP) {
    v  = kval[(size_t)i * KTOP + lane];
    jt = kidx[(size_t)i * KTOP + lane];
    const int* oj = kidx + (size_t)jt * KTOP;
#pragma unroll
    for (int t = 0; t < KTOP; ++t) mut = mut || (oj[t] == i);
  }
  float lv = mut ? v : -INFINITY;
#pragma unroll
  for (int off = 1; off < 16; off <<= 1) lv = fmaxf(lv, __shfl_xor(lv, off));
  float wexp = mut ? expf(v - lv) : 0.f;    // self is always mutual -> z >= 1
  float z = wexp;
#pragma unroll
  for (int off = 1; off < 16; off <<= 1) z += __shfl_xor(z, off);
  if (lane < KTOP) { sw[wv][lane] = wexp / z; sj[wv][lane] = jt; }
  __syncthreads();

  float a0 = 0.f, a1 = 0.f;
#pragma unroll
  for (int t = 0; t < KTOP; ++t) {
    float wt = sw[wv][t];
    if (wt != 0.f) {
      int j = sj[wv][t];
      int xr = (j >> 7) * XROW + KSHOT + (j & 127);
      const float* qr = x + (size_t)xr * D;
      a0 += wt * qr[lane];
      a1 += wt * qr[64 + lane];
    }
  }
  float ss = a0 * a0 + a1 * a1;
#pragma unroll
  for (int off = 1; off < 64; off <<= 1) ss += __shfl_xor(ss, off);
  float rn = 1.0f / fmaxf(sqrtf(ss), EPSV);
  an[wv][lane]      = a0 * rn;
  an[wv][64 + lane] = a1 * rn;
  __syncthreads();

  float acc = 0.f;
#pragma unroll 8
  for (int d = 0; d < D; ++d) acc += an[wv][d] * protnT[d * NCLS + lane];
  out[(size_t)i * NCLS + lane] = taop[0] * acc;
}

// ---------------------------------------------------------------------------
extern "C" void kernel_launch(void* const* d_in, const int* in_sizes, int n_in,
                              void* d_out, int out_size, void* d_ws, size_t ws_size,
                              hipStream_t stream) {
  const float* x   = (const float*)d_in[0];
  const float* tao = (const float*)d_in[1];
  float* out = (float*)d_out;

  // workspace layout (floats), total ~14 MB
  float* qn     = (float*)d_ws;                       // 8192*128
  float* pkv    = qn + (size_t)M * D;                 // 8192*16*9
  int*   pki    = (int*)(pkv + (size_t)M * NPART * KTOP);
  float* kval   = (float*)(pki + (size_t)M * NPART * KTOP);  // 8192*9
  int*   kidx   = (int*)(kval + (size_t)M * KTOP);
  float* protnT = (float*)(kidx + (size_t)M * KTOP);  // 128*64

  k0_proto<<<NCLS, 64, 0, stream>>>(x, protnT);
  k1_qnorm<<<M / 4, 256, 0, stream>>>(x, qn);
  k2_topk<<<(M / IB) * SJ, TPB, 0, stream>>>(qn, pkv, pki);
  k_merge<<<M / 256, 256, 0, stream>>>(pkv, pki, kval, kidx);
  k3_out<<<M / 4, 256, 0, stream>>>(x, kval, kidx, protnT, tao, out);
}